// Round 12
// baseline (106.077 us; speedup 1.0000x reference)
//
#include <hip/hip_runtime.h>

// NodeEncoder with interpolation, round 12.
//
// Ledger — dead: nt-stores (R3 -12%), per-wave MLP (R4 -7%), barrier drain
// (R7 null), block-coupled topology (R9 null), no-LDS strided stores (R10
// -48%). Confirmed: phase-separated prefetched reads (R5 +11%), LDS
// LUT-gather contiguous stores, fill-like zero-barrier 1-wave blocks (R11
// +4.4%, 105.0 us / 5.18 TB/s).
//
// R12 single change: 1024 -> 2048 single-wave blocks (4 -> 8 waves/CU).
// Theory: each store depends on a ~120-cyc ds_read; with only 4 waves/CU
// the chip-wide outstanding-store pool is too shallow for the DRAM
// scheduler (the fill kernel's stores have zero input deps). Doubling
// resident waves doubles independent ds_read->store chains per CU.

#define K_TAB 16
#define N_Z   83
#define WSZ   64
#define CA    256                  // atoms per wave-chunk (1 KB z, 16 KB out)
#define INNER (CA / 16)            // 16 store iterations per chunk

typedef float v4f __attribute__((ext_vector_type(4)));

__global__ __launch_bounds__(WSZ) void node_encode_kernel(
    const float* __restrict__ z_in,
    float* __restrict__ out,
    int n_atoms, int n_chunks)
{
    __shared__ float lut[N_Z][K_TAB];   // 5.3 KB
    __shared__ float zl[2][CA];         // 2 x 1 KB, single-wave owned

    const int lane = threadIdx.x;       // one wave per block

    // ---- LUT init: rows lane and lane+64 (single wave, no barrier needed) ----
    constexpr float tab[K_TAB] = {0.f, 1.f, 6.f, 7.f, 8.f, 11.f, 13.f, 14.f,
                                  16.f, 17.f, 26.f, 29.f, 47.f, 78.f, 79.f, 83.f};
    for (int row = lane; row < N_Z; row += WSZ) {
        const float zf = (float)row;
        int j = 0;
        float zlo = tab[0];
        float zhi = tab[K_TAB - 1];
#pragma unroll
        for (int k = 0; k < K_TAB; ++k) {          // ascending: count < z, track z_lo
            const bool lt = (tab[k] < zf);
            j += lt ? 1 : 0;
            zlo = lt ? tab[k] : zlo;
        }
#pragma unroll
        for (int k = K_TAB - 2; k >= 0; --k) {     // descending: smallest entry >= z
            zhi = (tab[k] >= zf) ? tab[k] : zhi;
        }
        const bool exact = (zhi == zf);
        const float denom = exact ? 1.f : (zhi - zlo);
        const float inv   = 1.f / denom;
        const float whi   = exact ? 1.f : (zf - zlo) * inv;
        const float wlo   = exact ? 0.f : (zhi - zf) * inv;
        int jl = j - (exact ? 0 : 1);
        if (jl < 0) jl = 0;
#pragma unroll
        for (int c = 0; c < K_TAB; ++c) {
            lut[row][c] = (c == j ? whi : 0.f) + (c == jl ? wlo : 0.f);
        }
    }

    v4f* __restrict__ out4 = reinterpret_cast<v4f*>(out);
    const int nwaves = gridDim.x;       // 1 wave per block
    const int gwave  = blockIdx.x;

    // ---- prologue: load first chunk's z into registers ----
    int c = gwave;
    v4f zreg = {0.f, 0.f, 0.f, 0.f};
    if (c < n_chunks) {
        const int a0 = c * CA + lane * 4;
        if (a0 + 3 < n_atoms) {
            zreg = *reinterpret_cast<const v4f*>(&z_in[a0]);
        } else {
#pragma unroll
            for (int e = 0; e < 4; ++e)
                if (a0 + e < n_atoms) zreg[e] = z_in[a0 + e];
        }
    }

    // ---- zero-barrier phase loop ----
    int p = 0;
    for (; c < n_chunks; c += nwaves, ++p) {
        // publish current chunk's z (wave-private buffer; lgkmcnt orders RAW)
        *reinterpret_cast<v4f*>(&zl[p & 1][lane * 4]) = zreg;

        // prefetch next chunk's z under the store run
        const int cn = c + nwaves;
        if (cn < n_chunks) {
            const int a0 = cn * CA + lane * 4;
            if (a0 + 3 < n_atoms) {
                zreg = *reinterpret_cast<const v4f*>(&z_in[a0]);
            } else {
                v4f zt = {0.f, 0.f, 0.f, 0.f};
#pragma unroll
                for (int e = 0; e < 4; ++e)
                    if (a0 + e < n_atoms) zt[e] = z_in[a0 + e];
                zreg = zt;
            }
        }

        const float* __restrict__ zb = zl[p & 1];
        const long base4 = (long)c * (CA * 4);     // float4 index of chunk start
        if ((c + 1) * CA <= n_atoms) {
            // full chunk: 16 x (zi -> lut b128 -> contiguous 1 KB wave-store)
#pragma unroll
            for (int k = 0; k < INNER; ++k) {
                const int u  = k * WSZ + lane;
                const int zi = (int)zb[u >> 2];
                const v4f v  = *reinterpret_cast<const v4f*>(&lut[zi][(u & 3) << 2]);
                out4[base4 + u] = v;
            }
        } else {
            const long total4 = (long)n_atoms * 4;
            for (int k = 0; k < INNER; ++k) {
                const int u = k * WSZ + lane;
                const long g = base4 + u;
                if (g < total4) {
                    const int zi = (int)zb[u >> 2];
                    out4[g] = *reinterpret_cast<const v4f*>(&lut[zi][(u & 3) << 2]);
                }
            }
        }
    }
}

extern "C" void kernel_launch(void* const* d_in, const int* in_sizes, int n_in,
                              void* d_out, int out_size, void* d_ws, size_t ws_size,
                              hipStream_t stream) {
    const float* z = (const float*)d_in[0];
    float* out = (float*)d_out;
    const int n_atoms = in_sizes[0];

    const int n_chunks = (n_atoms + CA - 1) / CA;   // 31250 for 8M atoms
    const int grid = 2048;                          // 8 single-wave blocks/CU

    node_encode_kernel<<<grid, WSZ, 0, stream>>>(z, out, n_atoms, n_chunks);
}